// Round 6
// baseline (326.622 us; speedup 1.0000x reference)
//
#include <hip/hip_runtime.h>

#define B_ 2048
#define P_ 32
#define Q_ 65
#define O_ 16
#define H_ 32

typedef __attribute__((ext_vector_type(8))) short short8;
typedef __attribute__((ext_vector_type(4))) float f32x4;

union F4S8 { float4 f; short8 s; };

// exp path: prefer raw v_exp_f32 (exp2) with weights prescaled by 2*log2(e);
// fallback: __expf with weights prescaled by 2.
#if defined(__has_builtin)
# if __has_builtin(__builtin_amdgcn_exp2f)
#  define HAVE_EXP2 1
# endif
#endif
#ifdef HAVE_EXP2
#define SCALE_K 2.8853900817779268f
__device__ __forceinline__ float exp_z(float y) { return __builtin_amdgcn_exp2f(y); }
#else
#define SCALE_K 2.0f
__device__ __forceinline__ float exp_z(float y) { return __expf(y); }
#endif

// tanh(z) given y = SCALE_K*z (already prescaled): 1 - 2/(e^{2z}+1)
__device__ __forceinline__ float tanh_pre(float y) {
    float e = exp_z(y);
    return fmaf(-2.0f, __builtin_amdgcn_rcpf(e + 1.0f), 1.0f);
}

__device__ __forceinline__ unsigned short bf_rne(float f) {
    unsigned u = __float_as_uint(f);
    return (unsigned short)((u + 0x7FFFu + ((u >> 16) & 1u)) >> 16);
}

// Per-(pq,lane) register record: 9 float4 = 144B.
// w1a/w1b, b1a/b1b are prescaled by SCALE_K in MODE2 (raw in MODE1/0).
// h0/l0/h1/l1: hi/lo bf16 B-fragments of SCALE_K*W2 (always prescaled).
// ms = {SCALE_K*b2[col], SCALE_K*b2[col+16], w3[col], w3[col+16]}.
struct Rec {
    float4 w1a, w1b, b1a, b1b, h0, l0, h1, l1, ms;
};

template<int MODE>
__device__ __forceinline__ Rec load_rec(
    const float* __restrict__ rec, const float* __restrict__ w1,
    const float* __restrict__ b1, const float* __restrict__ w2f,
    const float* __restrict__ b2, const float* __restrict__ w3,
    int pq, int lane, int g, int col)
{
    Rec r;
    if (MODE == 2) {
        const float4* rp = reinterpret_cast<const float4*>(rec + ((size_t)pq * 64 + lane) * 36);
        r.w1a = rp[0]; r.w1b = rp[1]; r.b1a = rp[2]; r.b1b = rp[3];
        r.h0  = rp[4]; r.l0  = rp[5]; r.h1  = rp[6]; r.l1  = rp[7];
        r.ms  = rp[8];
    } else {
        const float4* w1p = reinterpret_cast<const float4*>(w1 + pq * H_ + g * 8);
        r.w1a = w1p[0]; r.w1b = w1p[1];
        const float4* b1p = reinterpret_cast<const float4*>(b1 + pq * H_ + g * 8);
        r.b1a = b1p[0]; r.b1b = b1p[1];
        if (MODE == 1) {
            const float4* fp = reinterpret_cast<const float4*>(w2f + ((size_t)pq * 64 + lane) * 16);
            r.h0 = fp[0]; r.l0 = fp[1]; r.h1 = fp[2]; r.l1 = fp[3];
        } else {
            const float* w2p = w2f + (size_t)pq * (H_ * H_);
            F4S8 u0, u1, u2, u3;
            #pragma unroll
            for (int jj = 0; jj < 8; ++jj) {
                float v0 = SCALE_K * w2p[(g * 8 + jj) * H_ + col];
                float v1 = SCALE_K * w2p[(g * 8 + jj) * H_ + 16 + col];
                unsigned q0 = __float_as_uint(v0);
                u0.s[jj] = (short)(q0 >> 16);
                u1.s[jj] = (short)(__float_as_uint(v0 - __uint_as_float(q0 & 0xFFFF0000u)) >> 16);
                unsigned q1 = __float_as_uint(v1);
                u2.s[jj] = (short)(q1 >> 16);
                u3.s[jj] = (short)(__float_as_uint(v1 - __uint_as_float(q1 & 0xFFFF0000u)) >> 16);
            }
            r.h0 = u0.f; r.l0 = u1.f; r.h1 = u2.f; r.l1 = u3.f;
        }
        r.ms = make_float4(SCALE_K * b2[pq * H_ + col], SCALE_K * b2[pq * H_ + 16 + col],
                           w3[pq * H_ + col], w3[pq * H_ + 16 + col]);
    }
    return r;
}

// One eval for 16 batch rows per wave; psum[r] accumulates layer-3 partials.
template<bool L1_PRESCALED>
__device__ __forceinline__ void eval_rec(const Rec& r, float xv, float psum[4])
{
    short8 ahi, alo;
#define L1STEP(j, W, Bc)                                                    \
    { float zz = fmaf(xv, (W), (Bc));                                       \
      float y  = L1_PRESCALED ? zz : zz * SCALE_K;                          \
      float tt = tanh_pre(y);                                               \
      unsigned uu = __float_as_uint(tt);                                    \
      ahi[j] = (short)(uu >> 16);                                           \
      float ll = tt - __uint_as_float(uu & 0xFFFF0000u);                    \
      alo[j] = (short)(__float_as_uint(ll) >> 16); }
    L1STEP(0, r.w1a.x, r.b1a.x)
    L1STEP(1, r.w1a.y, r.b1a.y)
    L1STEP(2, r.w1a.z, r.b1a.z)
    L1STEP(3, r.w1a.w, r.b1a.w)
    L1STEP(4, r.w1b.x, r.b1b.x)
    L1STEP(5, r.w1b.y, r.b1b.y)
    L1STEP(6, r.w1b.z, r.b1b.z)
    L1STEP(7, r.w1b.w, r.b1b.w)
#undef L1STEP

    F4S8 c0, c1, c2, c3;
    c0.f = r.h0; c1.f = r.l0; c2.f = r.h1; c3.f = r.l1;
    f32x4 acc0 = {r.ms.x, r.ms.x, r.ms.x, r.ms.x};
    f32x4 acc1 = {r.ms.y, r.ms.y, r.ms.y, r.ms.y};
    acc0 = __builtin_amdgcn_mfma_f32_16x16x32_bf16(ahi, c0.s, acc0, 0, 0, 0);
    acc0 = __builtin_amdgcn_mfma_f32_16x16x32_bf16(alo, c0.s, acc0, 0, 0, 0);
    acc0 = __builtin_amdgcn_mfma_f32_16x16x32_bf16(ahi, c1.s, acc0, 0, 0, 0);
    acc1 = __builtin_amdgcn_mfma_f32_16x16x32_bf16(ahi, c2.s, acc1, 0, 0, 0);
    acc1 = __builtin_amdgcn_mfma_f32_16x16x32_bf16(alo, c2.s, acc1, 0, 0, 0);
    acc1 = __builtin_amdgcn_mfma_f32_16x16x32_bf16(ahi, c3.s, acc1, 0, 0, 0);

    // layer-2 acc is always prescaled (frag & b2 carry SCALE_K)
    #pragma unroll
    for (int rr = 0; rr < 4; ++rr) {
        psum[rr] = fmaf(tanh_pre(acc0[rr]), r.ms.z, psum[rr]);
        psum[rr] = fmaf(tanh_pre(acc1[rr]), r.ms.w, psum[rr]);
    }
}

__device__ __forceinline__ void reduce_store(float psum[4], float b3sum,
                                             int lane, int g, int b0w,
                                             float* addr_base, int stride, bool atomic)
{
    #pragma unroll
    for (int rr = 0; rr < 4; ++rr) {
        psum[rr] += __shfl_xor(psum[rr], 1);
        psum[rr] += __shfl_xor(psum[rr], 2);
        psum[rr] += __shfl_xor(psum[rr], 4);
        psum[rr] += __shfl_xor(psum[rr], 8);
    }
    float v01 = (lane & 1) ? psum[1] : psum[0];
    float v23 = (lane & 1) ? psum[3] : psum[2];
    float v = (lane & 2) ? v23 : v01;
    if ((lane & 15) < 4) {
        int row = b0w + g * 4 + (lane & 3);
        float* a = addr_base + (size_t)row * stride;
        if (atomic) atomicAdd(a, v + b3sum);
        else        *a = v + b3sum;
    }
}

// ---------------------------------------------------------------------------
// Stage 1: sT[q][b] = sum_p psi_{p,q}(x[b,p]).
// 1-D grid 2080 = 8 XCD-slices x 260; each XCD owns ~9 consecutive q's.
// ---------------------------------------------------------------------------
template<int MODE>
__global__ __launch_bounds__(256)
void psi_main(const float* __restrict__ x,
              const float* __restrict__ w1, const float* __restrict__ b1,
              const float* __restrict__ w2f, const float* __restrict__ b2,
              const float* __restrict__ w3, const float* __restrict__ b3,
              const float* __restrict__ rec, float* __restrict__ sT)
{
    const int id = blockIdx.x;
    const int j = (id & 7) * 260 + (id >> 3);   // bijective: 2080 = 8*260
    const int q = j >> 5;
    const int btile = j & 31;
    const int lane = threadIdx.x & 63;
    const int wid = threadIdx.x >> 6;
    const int g = lane >> 4, col = lane & 15;
    const int b0w = btile * 64 + wid * 16;
    const float* xrow = x + (size_t)(b0w + col) * P_;

    float psum[4] = {0.f, 0.f, 0.f, 0.f};
    float b3sum = 0.f;

    Rec cur = load_rec<MODE>(rec, w1, b1, w2f, b2, w3, q, lane, g, col);
    float xv = xrow[0];

    #pragma unroll 2
    for (int p = 0; p < P_; ++p) {
        const int pn = (p + 1 < P_) ? p + 1 : P_ - 1;
        Rec nxt = load_rec<MODE>(rec, w1, b1, w2f, b2, w3, pn * Q_ + q, lane, g, col);
        float xn = xrow[pn];
        b3sum += b3[p * Q_ + q];
        eval_rec<(MODE == 2)>(cur, xv, psum);
        cur = nxt; xv = xn;
    }

    reduce_store(psum, b3sum, lane, g, b0w, sT + (size_t)q * B_, 1, false);
}

// ---------------------------------------------------------------------------
// Stage 2: out[b][o] += sum_{q in 5-group} phi_{q,o}(sT[q][b]).
// 1-D grid 6656 = 8 x 832; 13 q-groups of 5 -> good occupancy, L2-local.
// ---------------------------------------------------------------------------
template<int MODE>
__global__ __launch_bounds__(256)
void phi_main(const float* __restrict__ sT,
              const float* __restrict__ w1, const float* __restrict__ b1,
              const float* __restrict__ w2f, const float* __restrict__ b2,
              const float* __restrict__ w3, const float* __restrict__ b3,
              const float* __restrict__ rec, float* __restrict__ out)
{
    const int id = blockIdx.x;
    const int j = (id & 7) * 832 + (id >> 3);   // bijective: 6656 = 8*832
    const int qg = j >> 9;                      // 0..12
    const int rem = j & 511;
    const int o = rem >> 5;
    const int btile = rem & 31;
    const int lane = threadIdx.x & 63;
    const int wid = threadIdx.x >> 6;
    const int g = lane >> 4, col = lane & 15;
    const int b0w = btile * 64 + wid * 16;

    float psum[4] = {0.f, 0.f, 0.f, 0.f};
    float b3sum = 0.f;

    const int q0 = qg * 5;
    Rec cur = load_rec<MODE>(rec, w1, b1, w2f, b2, w3, q0 * O_ + o, lane, g, col);
    float sv = sT[(size_t)q0 * B_ + b0w + col];

    #pragma unroll
    for (int i = 0; i < 5; ++i) {
        const int in_ = (i + 1 < 5) ? i + 1 : 4;
        const int qn = q0 + in_;
        Rec nxt = load_rec<MODE>(rec, w1, b1, w2f, b2, w3, qn * O_ + o, lane, g, col);
        float sn = sT[(size_t)qn * B_ + b0w + col];
        b3sum += b3[(q0 + i) * O_ + o];
        eval_rec<(MODE == 2)>(cur, sv, psum);
        cur = nxt; sv = sn;
    }

    // NOTE: base must include the o-column offset (R5 bug: passed `out` alone,
    // collapsing all 16 columns into column 0).
    reduce_store(psum, b3sum, lane, g, b0w, out + o, O_, true);
}

// ---------------------------------------------------------------------------
// Prep kernels
// ---------------------------------------------------------------------------
__global__ __launch_bounds__(256)
void prep_rec(const float* __restrict__ w1, const float* __restrict__ b1,
              const float* __restrict__ w2, const float* __restrict__ b2,
              const float* __restrict__ w3, float* __restrict__ rec, int npairs)
{
    int idx = blockIdx.x * 256 + threadIdx.x;
    if (idx >= npairs * 64) return;
    int pq = idx >> 6, lane = idx & 63;
    int g = lane >> 4, col = lane & 15;

    __attribute__((aligned(16))) float o[36];
    #pragma unroll
    for (int jj = 0; jj < 8; ++jj) {
        o[jj]     = SCALE_K * w1[pq * H_ + g * 8 + jj];
        o[8 + jj] = SCALE_K * b1[pq * H_ + g * 8 + jj];
    }
    const float* Wp = w2 + (size_t)pq * (H_ * H_);
    short8 h0v, l0v, h1v, l1v;
    #pragma unroll
    for (int jj = 0; jj < 8; ++jj) {
        float v0 = SCALE_K * Wp[(g * 8 + jj) * H_ + col];
        float v1 = SCALE_K * Wp[(g * 8 + jj) * H_ + 16 + col];
        unsigned short hb0 = bf_rne(v0);
        h0v[jj] = (short)hb0;
        l0v[jj] = (short)bf_rne(v0 - __uint_as_float(((unsigned)hb0) << 16));
        unsigned short hb1 = bf_rne(v1);
        h1v[jj] = (short)hb1;
        l1v[jj] = (short)bf_rne(v1 - __uint_as_float(((unsigned)hb1) << 16));
    }
    F4S8 a, b, c, d; a.s = h0v; b.s = l0v; c.s = h1v; d.s = l1v;
    *reinterpret_cast<float4*>(&o[16]) = a.f;
    *reinterpret_cast<float4*>(&o[20]) = b.f;
    *reinterpret_cast<float4*>(&o[24]) = c.f;
    *reinterpret_cast<float4*>(&o[28]) = d.f;
    o[32] = SCALE_K * b2[pq * H_ + col];
    o[33] = SCALE_K * b2[pq * H_ + 16 + col];
    o[34] = w3[pq * H_ + col];
    o[35] = w3[pq * H_ + 16 + col];

    float4* op = reinterpret_cast<float4*>(rec + (size_t)idx * 36);
    #pragma unroll
    for (int k = 0; k < 9; ++k) op[k] = *reinterpret_cast<float4*>(&o[k * 4]);
}

__global__ __launch_bounds__(256)
void prep_frag(const float* __restrict__ w2, float* __restrict__ frag, int npairs)
{
    int idx = blockIdx.x * 256 + threadIdx.x;
    if (idx >= npairs * 64) return;
    int pq = idx >> 6, lane = idx & 63;
    int g = lane >> 4, col = lane & 15;
    const float* Wp = w2 + (size_t)pq * (H_ * H_);

    short8 h0v, l0v, h1v, l1v;
    #pragma unroll
    for (int jj = 0; jj < 8; ++jj) {
        float v0 = SCALE_K * Wp[(g * 8 + jj) * H_ + col];
        float v1 = SCALE_K * Wp[(g * 8 + jj) * H_ + 16 + col];
        unsigned short hb0 = bf_rne(v0);
        h0v[jj] = (short)hb0;
        l0v[jj] = (short)bf_rne(v0 - __uint_as_float(((unsigned)hb0) << 16));
        unsigned short hb1 = bf_rne(v1);
        h1v[jj] = (short)hb1;
        l1v[jj] = (short)bf_rne(v1 - __uint_as_float(((unsigned)hb1) << 16));
    }
    F4S8 a, b, c, d; a.s = h0v; b.s = l0v; c.s = h1v; d.s = l1v;
    float4* op = reinterpret_cast<float4*>(frag + (size_t)idx * 16);
    op[0] = a.f; op[1] = b.f; op[2] = c.f; op[3] = d.f;
}

extern "C" void kernel_launch(void* const* d_in, const int* in_sizes, int n_in,
                              void* d_out, int out_size, void* d_ws, size_t ws_size,
                              hipStream_t stream) {
    const float* x      = (const float*)d_in[0];
    const float* psi_w1 = (const float*)d_in[1];
    const float* psi_b1 = (const float*)d_in[2];
    const float* psi_w2 = (const float*)d_in[3];
    const float* psi_b2 = (const float*)d_in[4];
    const float* psi_w3 = (const float*)d_in[5];
    const float* psi_b3 = (const float*)d_in[6];
    const float* phi_w1 = (const float*)d_in[7];
    const float* phi_b1 = (const float*)d_in[8];
    const float* phi_w2 = (const float*)d_in[9];
    const float* phi_b2 = (const float*)d_in[10];
    const float* phi_w3 = (const float*)d_in[11];
    const float* phi_b3 = (const float*)d_in[12];
    float* out = (float*)d_out;

    const size_t ST    = (size_t)B_ * Q_ * sizeof(float);   //   532,480
    const size_t REC1  = (size_t)P_ * Q_ * 64 * 144;        // 19,169,280
    const size_t REC2  = (size_t)Q_ * O_ * 64 * 144;        //  9,584,640
    const size_t FR1   = (size_t)P_ * Q_ * 64 * 64;         //  8,519,680
    const size_t FR2   = (size_t)Q_ * O_ * 64 * 64;         //  4,259,840

    float* sT = (float*)d_ws;
    hipMemsetAsync(out, 0, (size_t)B_ * O_ * sizeof(float), stream);

    if (ws_size >= ST + REC1 + REC2) {
        float* rec1 = (float*)((char*)d_ws + ST);
        float* rec2 = (float*)((char*)d_ws + ST + REC1);
        prep_rec<<<(P_ * Q_ * 64 + 255) / 256, 256, 0, stream>>>(
            psi_w1, psi_b1, psi_w2, psi_b2, psi_w3, rec1, P_ * Q_);
        prep_rec<<<(Q_ * O_ * 64 + 255) / 256, 256, 0, stream>>>(
            phi_w1, phi_b1, phi_w2, phi_b2, phi_w3, rec2, Q_ * O_);
        psi_main<2><<<2080, 256, 0, stream>>>(
            x, psi_w1, psi_b1, psi_w2, psi_b2, psi_w3, psi_b3, rec1, sT);
        phi_main<2><<<6656, 256, 0, stream>>>(
            sT, phi_w1, phi_b1, phi_w2, phi_b2, phi_w3, phi_b3, rec2, out);
    } else if (ws_size >= ST + FR1 + FR2) {
        float* fr1 = (float*)((char*)d_ws + ST);
        float* fr2 = (float*)((char*)d_ws + ST + FR1);
        prep_frag<<<(P_ * Q_ * 64 + 255) / 256, 256, 0, stream>>>(psi_w2, fr1, P_ * Q_);
        prep_frag<<<(Q_ * O_ * 64 + 255) / 256, 256, 0, stream>>>(phi_w2, fr2, Q_ * O_);
        psi_main<1><<<2080, 256, 0, stream>>>(
            x, psi_w1, psi_b1, fr1, psi_b2, psi_w3, psi_b3, fr1, sT);
        phi_main<1><<<6656, 256, 0, stream>>>(
            sT, phi_w1, phi_b1, fr2, phi_b2, phi_w3, phi_b3, fr2, out);
    } else {
        psi_main<0><<<2080, 256, 0, stream>>>(
            x, psi_w1, psi_b1, psi_w2, psi_b2, psi_w3, psi_b3, sT, sT);
        phi_main<0><<<6656, 256, 0, stream>>>(
            sT, phi_w1, phi_b1, phi_w2, phi_b2, phi_w3, phi_b3, sT, out);
    }
}

// Round 9
// 226.734 us; speedup vs baseline: 1.4406x; 1.4406x over previous
//
#include <hip/hip_runtime.h>

#define B_ 2048
#define P_ 32
#define Q_ 65
#define O_ 16
#define H_ 32

typedef __attribute__((ext_vector_type(8))) short short8;
typedef __attribute__((ext_vector_type(4))) float f32x4;

union F4S8 { float4 f; short8 s; };

#if defined(__has_builtin)
# if __has_builtin(__builtin_amdgcn_exp2f)
#  define HAVE_EXP2 1
# endif
#endif
#ifdef HAVE_EXP2
#define SCALE_K 2.8853900817779268f   // 2*log2(e)
__device__ __forceinline__ float exp_z(float y) { return __builtin_amdgcn_exp2f(y); }
#else
#define SCALE_K 2.0f
__device__ __forceinline__ float exp_z(float y) { return __expf(y); }
#endif

// tanh(z) given y = SCALE_K*z: 1 - 2/(e^{2z}+1); saturates at +/-inf.
__device__ __forceinline__ float tanh_pre(float y) {
    float e = exp_z(y);
    return fmaf(-2.0f, __builtin_amdgcn_rcpf(e + 1.0f), 1.0f);
}

__device__ __forceinline__ unsigned short bf_rne(float f) {
    unsigned u = __float_as_uint(f);
    return (unsigned short)((u + 0x7FFFu + ((u >> 16) & 1u)) >> 16);
}

// In-register record per (pq,lane).
struct Rec {
    float4 w1a, w1b, b1a, b1b;   // layer-1 weights/biases (g-group of 8)
    float4 h0, l0, h1, l1;       // W2 B-fragments hi/lo bf16 (prescaled)
    float4 ms;                    // {K*b2[col], K*b2[col+16], w3[col], w3[col+16]}
};

// MODE2 layouts:
//  fragc[pq]: 4 chunks x 64 lanes x 16B  (float4 idx = pq*256 + k*64 + lane)
//  shw[pq]:   128 floats: [0:32) K*w1, [32:64) K*b1,
//             [64:128) per-col float4 {K*b2[c], K*b2[c+16], w3[c], w3[c+16]}
template<int MODE>
__device__ __forceinline__ Rec load_rec(
    const float* __restrict__ fragc, const float* __restrict__ shw,
    const float* __restrict__ w1, const float* __restrict__ b1,
    const float* __restrict__ w2, const float* __restrict__ b2,
    const float* __restrict__ w3,
    int pq, int lane, int g, int col)
{
    Rec r;
    if (MODE == 2) {
        const float4* fp = reinterpret_cast<const float4*>(fragc) + (size_t)pq * 256 + lane;
        r.h0 = fp[0]; r.l0 = fp[64]; r.h1 = fp[128]; r.l1 = fp[192];
        const float4* a = reinterpret_cast<const float4*>(shw + (size_t)pq * 128);
        r.w1a = a[g * 2];     r.w1b = a[g * 2 + 1];
        r.b1a = a[8 + g * 2]; r.b1b = a[8 + g * 2 + 1];
        r.ms  = a[16 + col];
    } else {
        const float4* w1p = reinterpret_cast<const float4*>(w1 + pq * H_ + g * 8);
        r.w1a = w1p[0]; r.w1b = w1p[1];
        const float4* b1p = reinterpret_cast<const float4*>(b1 + pq * H_ + g * 8);
        r.b1a = b1p[0]; r.b1b = b1p[1];
        const float* w2p = w2 + (size_t)pq * (H_ * H_);
        F4S8 u0, u1, u2, u3;
        #pragma unroll
        for (int jj = 0; jj < 8; ++jj) {
            float v0 = SCALE_K * w2p[(g * 8 + jj) * H_ + col];
            float v1 = SCALE_K * w2p[(g * 8 + jj) * H_ + 16 + col];
            unsigned q0 = __float_as_uint(v0);
            u0.s[jj] = (short)(q0 >> 16);
            u1.s[jj] = (short)(__float_as_uint(v0 - __uint_as_float(q0 & 0xFFFF0000u)) >> 16);
            unsigned q1 = __float_as_uint(v1);
            u2.s[jj] = (short)(q1 >> 16);
            u3.s[jj] = (short)(__float_as_uint(v1 - __uint_as_float(q1 & 0xFFFF0000u)) >> 16);
        }
        r.h0 = u0.f; r.l0 = u1.f; r.h1 = u2.f; r.l1 = u3.f;
        r.ms = make_float4(SCALE_K * b2[pq * H_ + col], SCALE_K * b2[pq * H_ + 16 + col],
                           w3[pq * H_ + col], w3[pq * H_ + 16 + col]);
    }
    return r;
}

// One eval for 16 batch rows per wave; psum[r] accumulates layer-3 partials.
template<bool L1_PRESCALED>
__device__ __forceinline__ void eval_rec(const Rec& r, float xv, float psum[4])
{
    short8 ahi, alo;
#define L1STEP(j, W, Bc)                                                    \
    { float zz = fmaf(xv, (W), (Bc));                                       \
      float y  = L1_PRESCALED ? zz : zz * SCALE_K;                          \
      float tt = tanh_pre(y);                                               \
      unsigned uu = __float_as_uint(tt);                                    \
      ahi[j] = (short)(uu >> 16);                                           \
      float ll = tt - __uint_as_float(uu & 0xFFFF0000u);                    \
      alo[j] = (short)(__float_as_uint(ll) >> 16); }
    L1STEP(0, r.w1a.x, r.b1a.x)
    L1STEP(1, r.w1a.y, r.b1a.y)
    L1STEP(2, r.w1a.z, r.b1a.z)
    L1STEP(3, r.w1a.w, r.b1a.w)
    L1STEP(4, r.w1b.x, r.b1b.x)
    L1STEP(5, r.w1b.y, r.b1b.y)
    L1STEP(6, r.w1b.z, r.b1b.z)
    L1STEP(7, r.w1b.w, r.b1b.w)
#undef L1STEP

    F4S8 c0, c1, c2, c3;
    c0.f = r.h0; c1.f = r.l0; c2.f = r.h1; c3.f = r.l1;
    f32x4 acc0 = {r.ms.x, r.ms.x, r.ms.x, r.ms.x};
    f32x4 acc1 = {r.ms.y, r.ms.y, r.ms.y, r.ms.y};
    acc0 = __builtin_amdgcn_mfma_f32_16x16x32_bf16(ahi, c0.s, acc0, 0, 0, 0);
    acc0 = __builtin_amdgcn_mfma_f32_16x16x32_bf16(alo, c0.s, acc0, 0, 0, 0);
    acc0 = __builtin_amdgcn_mfma_f32_16x16x32_bf16(ahi, c1.s, acc0, 0, 0, 0);
    acc1 = __builtin_amdgcn_mfma_f32_16x16x32_bf16(ahi, c2.s, acc1, 0, 0, 0);
    acc1 = __builtin_amdgcn_mfma_f32_16x16x32_bf16(alo, c2.s, acc1, 0, 0, 0);
    acc1 = __builtin_amdgcn_mfma_f32_16x16x32_bf16(ahi, c3.s, acc1, 0, 0, 0);

    #pragma unroll
    for (int rr = 0; rr < 4; ++rr) {
        psum[rr] = fmaf(tanh_pre(acc0[rr]), r.ms.z, psum[rr]);
        psum[rr] = fmaf(tanh_pre(acc1[rr]), r.ms.w, psum[rr]);
    }
}

__device__ __forceinline__ void reduce_store(float psum[4], float b3sum,
                                             int lane, int g, int b0w,
                                             float* addr_base, int stride, bool atomic)
{
    #pragma unroll
    for (int rr = 0; rr < 4; ++rr) {
        psum[rr] += __shfl_xor(psum[rr], 1);
        psum[rr] += __shfl_xor(psum[rr], 2);
        psum[rr] += __shfl_xor(psum[rr], 4);
        psum[rr] += __shfl_xor(psum[rr], 8);
    }
    float v01 = (lane & 1) ? psum[1] : psum[0];
    float v23 = (lane & 1) ? psum[3] : psum[2];
    float v = (lane & 2) ? v23 : v01;
    if ((lane & 15) < 4) {
        int row = b0w + g * 4 + (lane & 3);
        float* a = addr_base + (size_t)row * stride;
        if (atomic) atomicAdd(a, v + b3sum);
        else        *a = v + b3sum;
    }
}

// ---------------------------------------------------------------------------
// Stage 1: sT[q][b] = sum_p psi_{p,q}(x[b,p]).
// 1-D grid 2080 = 8 XCD-slices x 260 (bijective); L2-local weights per XCD.
// ---------------------------------------------------------------------------
template<int MODE>
__global__ __launch_bounds__(256)
void psi_main(const float* __restrict__ x, const float* __restrict__ xT,
              const float* __restrict__ w1, const float* __restrict__ b1,
              const float* __restrict__ w2, const float* __restrict__ b2,
              const float* __restrict__ w3, const float* __restrict__ b3,
              const float* __restrict__ fragc, const float* __restrict__ shw,
              float* __restrict__ sT)
{
    const int id = blockIdx.x;
    const int j = (id & 7) * 260 + (id >> 3);   // bijective: 2080 = 8*260
    const int q = j >> 5;
    const int btile = j & 31;
    const int lane = threadIdx.x & 63;
    const int wid = threadIdx.x >> 6;
    const int g = lane >> 4, col = lane & 15;
    const int b0w = btile * 64 + wid * 16;

    float psum[4] = {0.f, 0.f, 0.f, 0.f};
    float b3sum = 0.f;

    Rec cur = load_rec<MODE>(fragc, shw, w1, b1, w2, b2, w3, q, lane, g, col);
    float xv = (MODE == 2) ? xT[b0w + col] : x[(size_t)(b0w + col) * P_];

    #pragma unroll 2
    for (int p = 0; p < P_; ++p) {
        const int pn = (p + 1 < P_) ? p + 1 : P_ - 1;
        Rec nxt = load_rec<MODE>(fragc, shw, w1, b1, w2, b2, w3,
                                 pn * Q_ + q, lane, g, col);
        float xn = (MODE == 2) ? xT[(size_t)pn * B_ + b0w + col]
                               : x[(size_t)(b0w + col) * P_ + pn];
        b3sum += b3[p * Q_ + q];
        eval_rec<(MODE == 2)>(cur, xv, psum);
        cur = nxt; xv = xn;
    }

    reduce_store(psum, b3sum, lane, g, b0w, sT + (size_t)q * B_, 1, false);
}

// ---------------------------------------------------------------------------
// Stage 2: out[b][o] += sum_{q in 5-group} phi_{q,o}(sT[q][b]).
// 1-D grid 6656 = 8 x 832 (bijective).
// ---------------------------------------------------------------------------
template<int MODE>
__global__ __launch_bounds__(256)
void phi_main(const float* __restrict__ sT,
              const float* __restrict__ w1, const float* __restrict__ b1,
              const float* __restrict__ w2, const float* __restrict__ b2,
              const float* __restrict__ w3, const float* __restrict__ b3,
              const float* __restrict__ fragc, const float* __restrict__ shw,
              float* __restrict__ out)
{
    const int id = blockIdx.x;
    const int j = (id & 7) * 832 + (id >> 3);   // bijective: 6656 = 8*832
    const int qg = j >> 9;                      // 0..12
    const int rem = j & 511;
    const int o = rem >> 5;
    const int btile = rem & 31;
    const int lane = threadIdx.x & 63;
    const int wid = threadIdx.x >> 6;
    const int g = lane >> 4, col = lane & 15;
    const int b0w = btile * 64 + wid * 16;

    float psum[4] = {0.f, 0.f, 0.f, 0.f};
    float b3sum = 0.f;

    const int q0 = qg * 5;
    Rec cur = load_rec<MODE>(fragc, shw, w1, b1, w2, b2, w3, q0 * O_ + o, lane, g, col);
    float sv = sT[(size_t)q0 * B_ + b0w + col];

    #pragma unroll
    for (int i = 0; i < 5; ++i) {
        const int in_ = (i + 1 < 5) ? i + 1 : 4;
        const int qn = q0 + in_;
        Rec nxt = load_rec<MODE>(fragc, shw, w1, b1, w2, b2, w3,
                                 qn * O_ + o, lane, g, col);
        float sn = sT[(size_t)qn * B_ + b0w + col];
        b3sum += b3[(q0 + i) * O_ + o];
        eval_rec<(MODE == 2)>(cur, sv, psum);
        cur = nxt; sv = sn;
    }

    // base includes the o-column offset (R5 bug fixed in R6, kept).
    reduce_store(psum, b3sum, lane, g, b0w, out + o, O_, true);
}

// ---------------------------------------------------------------------------
// Prep kernels
// ---------------------------------------------------------------------------
__global__ __launch_bounds__(256)
void prep_frag(const float* __restrict__ w2, float* __restrict__ frag, int npairs)
{
    int idx = blockIdx.x * 256 + threadIdx.x;
    if (idx >= npairs * 64) return;
    int pq = idx >> 6, lane = idx & 63;
    int g = lane >> 4, col = lane & 15;
    const float* Wp = w2 + (size_t)pq * (H_ * H_);

    short8 h0v, l0v, h1v, l1v;
    #pragma unroll
    for (int jj = 0; jj < 8; ++jj) {
        float v0 = SCALE_K * Wp[(g * 8 + jj) * H_ + col];
        float v1 = SCALE_K * Wp[(g * 8 + jj) * H_ + 16 + col];
        unsigned short hb0 = bf_rne(v0);
        h0v[jj] = (short)hb0;
        l0v[jj] = (short)bf_rne(v0 - __uint_as_float(((unsigned)hb0) << 16));
        unsigned short hb1 = bf_rne(v1);
        h1v[jj] = (short)hb1;
        l1v[jj] = (short)bf_rne(v1 - __uint_as_float(((unsigned)hb1) << 16));
    }
    F4S8 a, b, c, d; a.s = h0v; b.s = l0v; c.s = h1v; d.s = l1v;
    // chunk-interleaved: float4 idx = pq*256 + k*64 + lane
    float4* op = reinterpret_cast<float4*>(frag) + (size_t)pq * 256 + lane;
    op[0] = a.f; op[64] = b.f; op[128] = c.f; op[192] = d.f;
}

__global__ __launch_bounds__(256)
void prep_shw(const float* __restrict__ w1, const float* __restrict__ b1,
              const float* __restrict__ b2, const float* __restrict__ w3,
              float* __restrict__ shw, int npairs)
{
    int idx = blockIdx.x * 256 + threadIdx.x;
    if (idx >= npairs * 128) return;
    int pq = idx >> 7, i = idx & 127;
    float v;
    if (i < 32)       v = SCALE_K * w1[pq * H_ + i];
    else if (i < 64)  v = SCALE_K * b1[pq * H_ + (i - 32)];
    else {
        int c = (i - 64) >> 2, rr = i & 3;
        v = (rr == 0) ? SCALE_K * b2[pq * H_ + c]
          : (rr == 1) ? SCALE_K * b2[pq * H_ + c + 16]
          : (rr == 2) ? w3[pq * H_ + c]
          :             w3[pq * H_ + c + 16];
    }
    shw[(size_t)pq * 128 + i] = v;
}

__global__ __launch_bounds__(256)
void prep_xT(const float* __restrict__ x, float* __restrict__ xT)
{
    int idx = blockIdx.x * 256 + threadIdx.x;   // B_*P_ = 65536 total
    int b = idx >> 5, p = idx & 31;
    xT[(size_t)p * B_ + b] = x[idx];
}

extern "C" void kernel_launch(void* const* d_in, const int* in_sizes, int n_in,
                              void* d_out, int out_size, void* d_ws, size_t ws_size,
                              hipStream_t stream) {
    const float* x      = (const float*)d_in[0];
    const float* psi_w1 = (const float*)d_in[1];
    const float* psi_b1 = (const float*)d_in[2];
    const float* psi_w2 = (const float*)d_in[3];
    const float* psi_b2 = (const float*)d_in[4];
    const float* psi_w3 = (const float*)d_in[5];
    const float* psi_b3 = (const float*)d_in[6];
    const float* phi_w1 = (const float*)d_in[7];
    const float* phi_b1 = (const float*)d_in[8];
    const float* phi_w2 = (const float*)d_in[9];
    const float* phi_b2 = (const float*)d_in[10];
    const float* phi_w3 = (const float*)d_in[11];
    const float* phi_b3 = (const float*)d_in[12];
    float* out = (float*)d_out;

    const size_t ST  = (size_t)B_ * Q_ * sizeof(float);     //   532,480
    const size_t XT  = (size_t)B_ * P_ * sizeof(float);     //   262,144
    const size_t FR1 = (size_t)P_ * Q_ * 64 * 64;           //  8,519,680
    const size_t FR2 = (size_t)Q_ * O_ * 64 * 64;           //  4,259,840
    const size_t SH1 = (size_t)P_ * Q_ * 128 * 4;           //  1,064,960
    const size_t SH2 = (size_t)Q_ * O_ * 128 * 4;           //    532,480

    float* sT = (float*)d_ws;
    hipMemsetAsync(out, 0, (size_t)B_ * O_ * sizeof(float), stream);

    if (ws_size >= ST + XT + FR1 + FR2 + SH1 + SH2) {
        char* base = (char*)d_ws + ST;
        float* xT   = (float*)base;                   base += XT;
        float* fr1  = (float*)base;                   base += FR1;
        float* fr2  = (float*)base;                   base += FR2;
        float* sh1  = (float*)base;                   base += SH1;
        float* sh2  = (float*)base;

        prep_xT<<<(B_ * P_) / 256, 256, 0, stream>>>(x, xT);
        prep_frag<<<(P_ * Q_ * 64 + 255) / 256, 256, 0, stream>>>(psi_w2, fr1, P_ * Q_);
        prep_frag<<<(Q_ * O_ * 64 + 255) / 256, 256, 0, stream>>>(phi_w2, fr2, Q_ * O_);
        prep_shw<<<(P_ * Q_ * 128 + 255) / 256, 256, 0, stream>>>(
            psi_w1, psi_b1, psi_b2, psi_w3, sh1, P_ * Q_);
        prep_shw<<<(Q_ * O_ * 128 + 255) / 256, 256, 0, stream>>>(
            phi_w1, phi_b1, phi_b2, phi_w3, sh2, Q_ * O_);

        psi_main<2><<<2080, 256, 0, stream>>>(
            x, xT, psi_w1, psi_b1, psi_w2, psi_b2, psi_w3, psi_b3, fr1, sh1, sT);
        phi_main<2><<<6656, 256, 0, stream>>>(
            sT, phi_w1, phi_b1, phi_w2, phi_b2, phi_w3, phi_b3, fr2, sh2, out);
    } else {
        psi_main<0><<<2080, 256, 0, stream>>>(
            x, x, psi_w1, psi_b1, psi_w2, psi_b2, psi_w3, psi_b3, sT, sT, sT);
        phi_main<0><<<6656, 256, 0, stream>>>(
            sT, phi_w1, phi_b1, phi_w2, phi_b2, phi_w3, phi_b3, sT, sT, out);
    }
}

// Round 10
// 220.262 us; speedup vs baseline: 1.4829x; 1.0294x over previous
//
#include <hip/hip_runtime.h>

#define B_ 2048
#define P_ 32
#define Q_ 65
#define O_ 16
#define H_ 32

typedef __attribute__((ext_vector_type(8))) short short8;
typedef __attribute__((ext_vector_type(4))) float f32x4;

union F4S8 { float4 f; short8 s; };

#if defined(__has_builtin)
# if __has_builtin(__builtin_amdgcn_exp2f)
#  define HAVE_EXP2 1
# endif
#endif
#ifdef HAVE_EXP2
#define SCALE_K 2.8853900817779268f   // 2*log2(e)
__device__ __forceinline__ float exp_z(float y) { return __builtin_amdgcn_exp2f(y); }
#else
#define SCALE_K 2.0f
__device__ __forceinline__ float exp_z(float y) { return __expf(y); }
#endif

// tanh(z) given y = SCALE_K*z: 1 - 2/(e^{2z}+1); saturates at +/-inf.
__device__ __forceinline__ float tanh_pre(float y) {
    float e = exp_z(y);
    return fmaf(-2.0f, __builtin_amdgcn_rcpf(e + 1.0f), 1.0f);
}

__device__ __forceinline__ unsigned short bf_rne(float f) {
    unsigned u = __float_as_uint(f);
    return (unsigned short)((u + 0x7FFFu + ((u >> 16) & 1u)) >> 16);
}

// In-register record per (pq,lane).
struct Rec {
    float4 w1a, w1b, b1a, b1b;   // layer-1 weights/biases (g-group of 8)
    float4 h0, l0, h1, l1;       // W2 B-fragments hi/lo bf16 (prescaled)
    float4 ms;                    // {K*b2[col], K*b2[col+16], w3[col], w3[col+16]}
};

// MODE2 layouts:
//  fragc[pq]: 4 chunks x 64 lanes x 16B  (float4 idx = pq*256 + k*64 + lane)
//  shw[pq]:   128 floats: [0:32) K*w1, [32:64) K*b1,
//             [64:128) per-col float4 {K*b2[c], K*b2[c+16], w3[c], w3[c+16]}
template<int MODE>
__device__ __forceinline__ Rec load_rec(
    const float* __restrict__ fragc, const float* __restrict__ shw,
    const float* __restrict__ w1, const float* __restrict__ b1,
    const float* __restrict__ w2, const float* __restrict__ b2,
    const float* __restrict__ w3,
    int pq, int lane, int g, int col)
{
    Rec r;
    if (MODE == 2) {
        const float4* fp = reinterpret_cast<const float4*>(fragc) + (size_t)pq * 256 + lane;
        r.h0 = fp[0]; r.l0 = fp[64]; r.h1 = fp[128]; r.l1 = fp[192];
        const float4* a = reinterpret_cast<const float4*>(shw + (size_t)pq * 128);
        r.w1a = a[g * 2];     r.w1b = a[g * 2 + 1];
        r.b1a = a[8 + g * 2]; r.b1b = a[8 + g * 2 + 1];
        r.ms  = a[16 + col];
    } else {
        const float4* w1p = reinterpret_cast<const float4*>(w1 + pq * H_ + g * 8);
        r.w1a = w1p[0]; r.w1b = w1p[1];
        const float4* b1p = reinterpret_cast<const float4*>(b1 + pq * H_ + g * 8);
        r.b1a = b1p[0]; r.b1b = b1p[1];
        const float* w2p = w2 + (size_t)pq * (H_ * H_);
        F4S8 u0, u1, u2, u3;
        #pragma unroll
        for (int jj = 0; jj < 8; ++jj) {
            float v0 = SCALE_K * w2p[(g * 8 + jj) * H_ + col];
            float v1 = SCALE_K * w2p[(g * 8 + jj) * H_ + 16 + col];
            unsigned q0 = __float_as_uint(v0);
            u0.s[jj] = (short)(q0 >> 16);
            u1.s[jj] = (short)(__float_as_uint(v0 - __uint_as_float(q0 & 0xFFFF0000u)) >> 16);
            unsigned q1 = __float_as_uint(v1);
            u2.s[jj] = (short)(q1 >> 16);
            u3.s[jj] = (short)(__float_as_uint(v1 - __uint_as_float(q1 & 0xFFFF0000u)) >> 16);
        }
        r.h0 = u0.f; r.l0 = u1.f; r.h1 = u2.f; r.l1 = u3.f;
        r.ms = make_float4(SCALE_K * b2[pq * H_ + col], SCALE_K * b2[pq * H_ + 16 + col],
                           w3[pq * H_ + col], w3[pq * H_ + 16 + col]);
    }
    return r;
}

// One eval for 16 batch rows per wave; psum[r] accumulates layer-3 partials.
template<bool L1_PRESCALED>
__device__ __forceinline__ void eval_rec(const Rec& r, float xv, float psum[4])
{
    short8 ahi, alo;
#define L1STEP(j, W, Bc)                                                    \
    { float zz = fmaf(xv, (W), (Bc));                                       \
      float y  = L1_PRESCALED ? zz : zz * SCALE_K;                          \
      float tt = tanh_pre(y);                                               \
      unsigned uu = __float_as_uint(tt);                                    \
      ahi[j] = (short)(uu >> 16);                                           \
      float ll = tt - __uint_as_float(uu & 0xFFFF0000u);                    \
      alo[j] = (short)(__float_as_uint(ll) >> 16); }
    L1STEP(0, r.w1a.x, r.b1a.x)
    L1STEP(1, r.w1a.y, r.b1a.y)
    L1STEP(2, r.w1a.z, r.b1a.z)
    L1STEP(3, r.w1a.w, r.b1a.w)
    L1STEP(4, r.w1b.x, r.b1b.x)
    L1STEP(5, r.w1b.y, r.b1b.y)
    L1STEP(6, r.w1b.z, r.b1b.z)
    L1STEP(7, r.w1b.w, r.b1b.w)
#undef L1STEP

    F4S8 c0, c1, c2, c3;
    c0.f = r.h0; c1.f = r.l0; c2.f = r.h1; c3.f = r.l1;
    f32x4 acc0 = {r.ms.x, r.ms.x, r.ms.x, r.ms.x};
    f32x4 acc1 = {r.ms.y, r.ms.y, r.ms.y, r.ms.y};
    acc0 = __builtin_amdgcn_mfma_f32_16x16x32_bf16(ahi, c0.s, acc0, 0, 0, 0);
    acc0 = __builtin_amdgcn_mfma_f32_16x16x32_bf16(alo, c0.s, acc0, 0, 0, 0);
    acc0 = __builtin_amdgcn_mfma_f32_16x16x32_bf16(ahi, c1.s, acc0, 0, 0, 0);
    acc1 = __builtin_amdgcn_mfma_f32_16x16x32_bf16(ahi, c2.s, acc1, 0, 0, 0);
    acc1 = __builtin_amdgcn_mfma_f32_16x16x32_bf16(alo, c2.s, acc1, 0, 0, 0);
    acc1 = __builtin_amdgcn_mfma_f32_16x16x32_bf16(ahi, c3.s, acc1, 0, 0, 0);

    #pragma unroll
    for (int rr = 0; rr < 4; ++rr) {
        psum[rr] = fmaf(tanh_pre(acc0[rr]), r.ms.z, psum[rr]);
        psum[rr] = fmaf(tanh_pre(acc1[rr]), r.ms.w, psum[rr]);
    }
}

__device__ __forceinline__ void reduce_store(float psum[4], float b3sum,
                                             int lane, int g, int b0w,
                                             float* addr_base, int stride, bool atomic)
{
    #pragma unroll
    for (int rr = 0; rr < 4; ++rr) {
        psum[rr] += __shfl_xor(psum[rr], 1);
        psum[rr] += __shfl_xor(psum[rr], 2);
        psum[rr] += __shfl_xor(psum[rr], 4);
        psum[rr] += __shfl_xor(psum[rr], 8);
    }
    float v01 = (lane & 1) ? psum[1] : psum[0];
    float v23 = (lane & 1) ? psum[3] : psum[2];
    float v = (lane & 2) ? v23 : v01;
    if ((lane & 15) < 4) {
        int row = b0w + g * 4 + (lane & 3);
        float* a = addr_base + (size_t)row * stride;
        if (atomic) atomicAdd(a, v + b3sum);
        else        *a = v + b3sum;
    }
}

// ---------------------------------------------------------------------------
// Stage 1: sT[q][b] = sum_p psi_{p,q}(x[b,p]).
// 1-D grid 2080 = 8 XCD-slices x 260 (bijective).
// ---------------------------------------------------------------------------
template<int MODE>
__global__ __launch_bounds__(256)
void psi_main(const float* __restrict__ x, const float* __restrict__ xT,
              const float* __restrict__ w1, const float* __restrict__ b1,
              const float* __restrict__ w2, const float* __restrict__ b2,
              const float* __restrict__ w3, const float* __restrict__ b3,
              const float* __restrict__ b3c,
              const float* __restrict__ fragc, const float* __restrict__ shw,
              float* __restrict__ sT)
{
    const int id = blockIdx.x;
    const int j = (id & 7) * 260 + (id >> 3);   // bijective: 2080 = 8*260
    const int q = j >> 5;
    const int btile = j & 31;
    const int lane = threadIdx.x & 63;
    const int wid = threadIdx.x >> 6;
    const int g = lane >> 4, col = lane & 15;
    const int b0w = btile * 64 + wid * 16;

    float psum[4] = {0.f, 0.f, 0.f, 0.f};
    float b3sum = (MODE == 2) ? b3c[q] : 0.f;

    Rec cur = load_rec<MODE>(fragc, shw, w1, b1, w2, b2, w3, q, lane, g, col);
    float xv = (MODE == 2) ? xT[b0w + col] : x[(size_t)(b0w + col) * P_];

    #pragma unroll 2
    for (int p = 0; p < P_; ++p) {
        const int pn = (p + 1 < P_) ? p + 1 : P_ - 1;
        Rec nxt = load_rec<MODE>(fragc, shw, w1, b1, w2, b2, w3,
                                 pn * Q_ + q, lane, g, col);
        float xn = (MODE == 2) ? xT[(size_t)pn * B_ + b0w + col]
                               : x[(size_t)(b0w + col) * P_ + pn];
        if (MODE != 2) b3sum += b3[p * Q_ + q];
        eval_rec<(MODE == 2)>(cur, xv, psum);
        cur = nxt; xv = xn;
    }

    reduce_store(psum, b3sum, lane, g, b0w, sT + (size_t)q * B_, 1, false);
}

// ---------------------------------------------------------------------------
// Stage 2: out[b][o] += sum_{q in 13-group} phi_{q,o}(sT[q][b]).
// 1-D grid 2560 = 8 x 320 (bijective); 5 qg-groups of 13 q's each.
// ---------------------------------------------------------------------------
template<int MODE>
__global__ __launch_bounds__(256)
void phi_main(const float* __restrict__ sT,
              const float* __restrict__ w1, const float* __restrict__ b1,
              const float* __restrict__ w2, const float* __restrict__ b2,
              const float* __restrict__ w3, const float* __restrict__ b3,
              const float* __restrict__ b3g,
              const float* __restrict__ fragc, const float* __restrict__ shw,
              float* __restrict__ out)
{
    const int id = blockIdx.x;
    const int j = (id & 7) * 320 + (id >> 3);   // bijective: 2560 = 8*320
    const int qg = j >> 9;                      // 0..4
    const int rem = j & 511;
    const int o = rem >> 5;
    const int btile = rem & 31;
    const int lane = threadIdx.x & 63;
    const int wid = threadIdx.x >> 6;
    const int g = lane >> 4, col = lane & 15;
    const int b0w = btile * 64 + wid * 16;

    float psum[4] = {0.f, 0.f, 0.f, 0.f};
    float b3sum = (MODE == 2) ? b3g[qg * O_ + o] : 0.f;

    const int q0 = qg * 13;
    Rec cur = load_rec<MODE>(fragc, shw, w1, b1, w2, b2, w3, q0 * O_ + o, lane, g, col);
    float sv = sT[(size_t)q0 * B_ + b0w + col];

    #pragma unroll 2
    for (int i = 0; i < 13; ++i) {
        const int in_ = (i + 1 < 13) ? i + 1 : 12;
        const int qn = q0 + in_;
        Rec nxt = load_rec<MODE>(fragc, shw, w1, b1, w2, b2, w3,
                                 qn * O_ + o, lane, g, col);
        float sn = sT[(size_t)qn * B_ + b0w + col];
        if (MODE != 2) b3sum += b3[(q0 + i) * O_ + o];
        eval_rec<(MODE == 2)>(cur, sv, psum);
        cur = nxt; sv = sn;
    }

    // base includes the o-column offset (R5 lesson).
    reduce_store(psum, b3sum, lane, g, b0w, out + o, O_, true);
}

// ---------------------------------------------------------------------------
// Single fused prep kernel: fragments, shared-weight blocks, xT, b3 sums.
// ---------------------------------------------------------------------------
__device__ __forceinline__ void do_frag(const float* __restrict__ w2,
                                        float* __restrict__ frag, int idx)
{
    int pq = idx >> 6, lane = idx & 63;
    int g = lane >> 4, col = lane & 15;
    const float* Wp = w2 + (size_t)pq * (H_ * H_);
    short8 h0v, l0v, h1v, l1v;
    #pragma unroll
    for (int jj = 0; jj < 8; ++jj) {
        float v0 = SCALE_K * Wp[(g * 8 + jj) * H_ + col];
        float v1 = SCALE_K * Wp[(g * 8 + jj) * H_ + 16 + col];
        unsigned short hb0 = bf_rne(v0);
        h0v[jj] = (short)hb0;
        l0v[jj] = (short)bf_rne(v0 - __uint_as_float(((unsigned)hb0) << 16));
        unsigned short hb1 = bf_rne(v1);
        h1v[jj] = (short)hb1;
        l1v[jj] = (short)bf_rne(v1 - __uint_as_float(((unsigned)hb1) << 16));
    }
    F4S8 a, b, c, d; a.s = h0v; b.s = l0v; c.s = h1v; d.s = l1v;
    float4* op = reinterpret_cast<float4*>(frag) + (size_t)pq * 256 + lane;
    op[0] = a.f; op[64] = b.f; op[128] = c.f; op[192] = d.f;
}

__device__ __forceinline__ void do_shw(const float* __restrict__ w1,
                                       const float* __restrict__ b1,
                                       const float* __restrict__ b2,
                                       const float* __restrict__ w3,
                                       float* __restrict__ shw, int idx)
{
    int pq = idx >> 7, i = idx & 127;
    float v;
    if (i < 32)       v = SCALE_K * w1[pq * H_ + i];
    else if (i < 64)  v = SCALE_K * b1[pq * H_ + (i - 32)];
    else {
        int c = (i - 64) >> 2, rr = i & 3;
        v = (rr == 0) ? SCALE_K * b2[pq * H_ + c]
          : (rr == 1) ? SCALE_K * b2[pq * H_ + c + 16]
          : (rr == 2) ? w3[pq * H_ + c]
          :             w3[pq * H_ + c + 16];
    }
    shw[(size_t)pq * 128 + i] = v;
}

#define N1 133120   // P*Q*64      fr1
#define N2 66560    // Q*O*64      fr2
#define N3 266240   // P*Q*128     sh1
#define N4 133120   // Q*O*128     sh2
#define N5 65536    // B*P         xT
#define C1 133120
#define C2 199680
#define C3 465920
#define C4 599040
#define C5 664576
#define C6 664641   // +Q   (b3c)
#define C7 664721   // +80  (b3g)

__global__ __launch_bounds__(256)
void prep_all(const float* __restrict__ psi_w1, const float* __restrict__ psi_b1,
              const float* __restrict__ psi_w2, const float* __restrict__ psi_b2,
              const float* __restrict__ psi_w3, const float* __restrict__ psi_b3,
              const float* __restrict__ phi_w1, const float* __restrict__ phi_b1,
              const float* __restrict__ phi_w2, const float* __restrict__ phi_b2,
              const float* __restrict__ phi_w3, const float* __restrict__ phi_b3,
              const float* __restrict__ x,
              float* __restrict__ fr1, float* __restrict__ fr2,
              float* __restrict__ sh1, float* __restrict__ sh2,
              float* __restrict__ xT, float* __restrict__ b3c,
              float* __restrict__ b3g)
{
    int t = blockIdx.x * 256 + threadIdx.x;
    if (t < C1) {
        do_frag(psi_w2, fr1, t);
    } else if (t < C2) {
        do_frag(phi_w2, fr2, t - C1);
    } else if (t < C3) {
        do_shw(psi_w1, psi_b1, psi_b2, psi_w3, sh1, t - C2);
    } else if (t < C4) {
        do_shw(phi_w1, phi_b1, phi_b2, phi_w3, sh2, t - C3);
    } else if (t < C5) {
        int idx = t - C4;
        int b = idx >> 5, p = idx & 31;
        xT[(size_t)p * B_ + b] = x[idx];
    } else if (t < C6) {
        int q = t - C5;
        float s = 0.f;
        for (int p = 0; p < P_; ++p) s += psi_b3[p * Q_ + q];
        b3c[q] = s;
    } else if (t < C7) {
        int idx = t - C6;          // qg*16 + o
        int qg = idx >> 4, o = idx & 15;
        float s = 0.f;
        for (int i = 0; i < 13; ++i) s += phi_b3[(qg * 13 + i) * O_ + o];
        b3g[idx] = s;
    }
}

extern "C" void kernel_launch(void* const* d_in, const int* in_sizes, int n_in,
                              void* d_out, int out_size, void* d_ws, size_t ws_size,
                              hipStream_t stream) {
    const float* x      = (const float*)d_in[0];
    const float* psi_w1 = (const float*)d_in[1];
    const float* psi_b1 = (const float*)d_in[2];
    const float* psi_w2 = (const float*)d_in[3];
    const float* psi_b2 = (const float*)d_in[4];
    const float* psi_w3 = (const float*)d_in[5];
    const float* psi_b3 = (const float*)d_in[6];
    const float* phi_w1 = (const float*)d_in[7];
    const float* phi_b1 = (const float*)d_in[8];
    const float* phi_w2 = (const float*)d_in[9];
    const float* phi_b2 = (const float*)d_in[10];
    const float* phi_w3 = (const float*)d_in[11];
    const float* phi_b3 = (const float*)d_in[12];
    float* out = (float*)d_out;

    const size_t ST  = (size_t)B_ * Q_ * sizeof(float);     //   532,480
    const size_t XT  = (size_t)B_ * P_ * sizeof(float);     //   262,144
    const size_t FR1 = (size_t)N1 * 64;                     //  8,519,680
    const size_t FR2 = (size_t)N2 * 64;                     //  4,259,840
    const size_t SH1 = (size_t)N3 * 4;                      //  1,064,960
    const size_t SH2 = (size_t)N4 * 4;                      //    532,480
    const size_t B3C = 320;                                 // 65 floats padded
    const size_t B3G = 320;                                 // 80 floats

    float* sT = (float*)d_ws;
    hipMemsetAsync(out, 0, (size_t)B_ * O_ * sizeof(float), stream);

    if (ws_size >= ST + XT + FR1 + FR2 + SH1 + SH2 + B3C + B3G) {
        char* base = (char*)d_ws + ST;
        float* xTp  = (float*)base;                   base += XT;
        float* fr1  = (float*)base;                   base += FR1;
        float* fr2  = (float*)base;                   base += FR2;
        float* sh1  = (float*)base;                   base += SH1;
        float* sh2  = (float*)base;                   base += SH2;
        float* b3c  = (float*)base;                   base += B3C;
        float* b3g  = (float*)base;

        prep_all<<<(C7 + 255) / 256, 256, 0, stream>>>(
            psi_w1, psi_b1, psi_w2, psi_b2, psi_w3, psi_b3,
            phi_w1, phi_b1, phi_w2, phi_b2, phi_w3, phi_b3,
            x, fr1, fr2, sh1, sh2, xTp, b3c, b3g);

        psi_main<2><<<2080, 256, 0, stream>>>(
            x, xTp, psi_w1, psi_b1, psi_w2, psi_b2, psi_w3, psi_b3, b3c,
            fr1, sh1, sT);
        phi_main<2><<<2560, 256, 0, stream>>>(
            sT, phi_w1, phi_b1, phi_w2, phi_b2, phi_w3, phi_b3, b3g,
            fr2, sh2, out);
    } else {
        psi_main<0><<<2080, 256, 0, stream>>>(
            x, x, psi_w1, psi_b1, psi_w2, psi_b2, psi_w3, psi_b3, (const float*)sT,
            sT, sT, sT);
        phi_main<0><<<2560, 256, 0, stream>>>(
            sT, phi_w1, phi_b1, phi_w2, phi_b2, phi_w3, phi_b3, (const float*)sT,
            sT, sT, out);
    }
}